// Round 1
// baseline (683.906 us; speedup 1.0000x reference)
//
#include <hip/hip_runtime.h>
#include <stdint.h>

typedef unsigned short u16;
typedef __attribute__((ext_vector_type(8))) short short8;
typedef __attribute__((ext_vector_type(4))) float f32x4;

// ---------- bf16 helpers (RNE, bit tricks — no dependence on hip_bf16 API) ----------
static __device__ __forceinline__ u16 f2bf(float f) {
    union { float f; uint32_t u; } c; c.f = f;
    uint32_t u = c.u;
    u += 0x7FFFu + ((u >> 16) & 1u);
    return (u16)(u >> 16);
}
static __device__ __forceinline__ float bf2f(u16 s) {
    union { uint32_t u; float f; } c; c.u = ((uint32_t)s) << 16;
    return c.f;
}

// ---------- problem constants ----------
#define D_IN   2048
#define D_OUT  2048
#define MTOT   32768   // B*T = 16*2048
#define RANK   16
#define RPAD   32      // rank padded to one BK tile
#define BK     32

// ---------- prep: W fp32 -> bf16 (row-major (d_out, d_in), already K-major) ----------
__global__ __launch_bounds__(256) void k_cast_w(const float* __restrict__ W, u16* __restrict__ Wb) {
    int i = (blockIdx.x * 256 + threadIdx.x) * 8;
    const float4* p = (const float4*)(W + i);
    float4 v0 = p[0], v1 = p[1];
    short8 o;
    o[0]=f2bf(v0.x); o[1]=f2bf(v0.y); o[2]=f2bf(v0.z); o[3]=f2bf(v0.w);
    o[4]=f2bf(v1.x); o[5]=f2bf(v1.y); o[6]=f2bf(v1.z); o[7]=f2bf(v1.w);
    *(short8*)(Wb + i) = o;
}

// ---------- prep: A (a, r, d) fp32 -> At (a, d, r) bf16 ----------
__global__ __launch_bounds__(256) void k_build_at(const float* __restrict__ A, u16* __restrict__ At) {
    int i = blockIdx.x * 256 + threadIdx.x;   // over 8*2048*16 = 262144
    int r = i & 15;
    int d = (i >> 4) & 2047;
    int a = i >> 15;
    At[i] = f2bf(A[((a * 16 + r) << 11) + d]);
}

// ---------- prep: Bm (a, n, r) fp32 -> Bp (a, n, RPAD) bf16, zero-padded r=16..31 ----------
__global__ __launch_bounds__(256) void k_build_bp(const float* __restrict__ Bm, u16* __restrict__ Bp) {
    int i = blockIdx.x * 256 + threadIdx.x;   // over 8*2048*32 = 524288
    int j = i & 31;
    int n = (i >> 5) & 2047;
    int a = i >> 16;
    float v = (j < 16) ? Bm[(((a << 11) + n) << 4) + j] : 0.0f;
    Bp[i] = f2bf(v);
}

// ---------- fused: cast x -> bf16 AND compute xa[m][r] = s * sum_d x[m][d]*A[r][d] ----------
// one row (m) per block; 256 threads, 8 d's per thread
__global__ __launch_bounds__(256) void k_cast_x_xa(
    const float* __restrict__ x, const u16* __restrict__ At,
    const float* __restrict__ scal, const int* __restrict__ aidx,
    u16* __restrict__ xb, u16* __restrict__ xa)
{
    const int m = blockIdx.x;
    const int a = aidx[m >> 11];              // T = 2048
    const int tid = threadIdx.x;
    const int d0 = tid << 3;

    const float* xr = x + (((size_t)m) << 11) + d0;
    float4 v0 = *(const float4*)xr;
    float4 v1 = *(const float4*)(xr + 4);
    float xv[8] = {v0.x, v0.y, v0.z, v0.w, v1.x, v1.y, v1.z, v1.w};

    short8 o;
    #pragma unroll
    for (int j = 0; j < 8; ++j) o[j] = f2bf(xv[j]);
    *(short8*)(xb + (((size_t)m) << 11) + d0) = o;

    float facc[16];
    #pragma unroll
    for (int r = 0; r < 16; ++r) facc[r] = 0.f;
    const u16* Ar = At + ((((size_t)a) << 11) + d0) * 16;
    #pragma unroll
    for (int j = 0; j < 8; ++j) {
        short8 a0 = *(const short8*)(Ar + j * 16);
        short8 a1 = *(const short8*)(Ar + j * 16 + 8);
        #pragma unroll
        for (int r = 0; r < 8; ++r) facc[r]     += xv[j] * bf2f((u16)a0[r]);
        #pragma unroll
        for (int r = 0; r < 8; ++r) facc[8 + r] += xv[j] * bf2f((u16)a1[r]);
    }
    // wave butterfly reduce (64 lanes)
    #pragma unroll
    for (int r = 0; r < 16; ++r) {
        float v = facc[r];
        #pragma unroll
        for (int off = 32; off > 0; off >>= 1) v += __shfl_xor(v, off);
        facc[r] = v;
    }
    __shared__ float red[4][16];
    const int lane = tid & 63, wid = tid >> 6;
    if (lane == 0) {
        #pragma unroll
        for (int r = 0; r < 16; ++r) red[wid][r] = facc[r];
    }
    __syncthreads();
    if (tid < RPAD) {
        float v = 0.f;
        if (tid < RANK) v = (red[0][tid] + red[1][tid] + red[2][tid] + red[3][tid]) * scal[a];
        xa[(((size_t)m) << 5) + tid] = f2bf(v);
    }
}

// ---------- GEMM + fused LoRA tail (m97 structure: 128x128 tile, BK=32, 4 waves) ----------
__device__ __forceinline__ void gload16(const u16* g, u16* l) {
    __builtin_amdgcn_global_load_lds(
        (const __attribute__((address_space(1))) void*)g,
        (__attribute__((address_space(3))) void*)l, 16, 0, 0);
}

__global__ __launch_bounds__(256) void k_gemm(
    const u16* __restrict__ xb, const u16* __restrict__ Wb,
    const u16* __restrict__ xa, const u16* __restrict__ Bp,
    const int* __restrict__ aidx, float* __restrict__ out)
{
    __shared__ __align__(16) u16 As[128 * BK];  // 8 KB
    __shared__ __align__(16) u16 Bs[128 * BK];  // 8 KB
    const int tid = threadIdx.x;
    const int bm = blockIdx.x >> 4;             // 256 m-blocks
    const int bn = blockIdx.x & 15;             // 16  n-blocks
    const int m0 = bm << 7, n0 = bn << 7;
    const int lane = tid & 63;
    const int wid = tid >> 6;
    const int wr = wid >> 1, wc = wid & 1;      // 2x2 wave grid, 64x64 per wave

    f32x4 acc[4][4];
    #pragma unroll
    for (int i = 0; i < 4; ++i)
        #pragma unroll
        for (int j = 0; j < 4; ++j) acc[i][j] = 0.0f;

    // staging: thread tid -> LDS bytes [tid*16, tid*16+16)  (row tid/4, k (tid%4)*8)
    const int srow  = tid >> 2;
    const int skoff = (tid & 3) << 3;
    const u16* gA = xb + (((size_t)(m0 + srow)) << 11) + skoff;
    const u16* gB = Wb + (((size_t)(n0 + srow)) << 11) + skoff;
    u16* lA = As + tid * 8;
    u16* lB = Bs + tid * 8;
    const size_t gstep = ((size_t)64) << 11;    // +64 rows in global

    // fragment read offsets
    const int arow = (wr << 6) + (lane & 15);
    const int brow = (wc << 6) + (lane & 15);
    const int koff = (lane >> 4) << 3;

    for (int kt = 0; kt < 64; ++kt) {
        const int k0 = kt << 5;
        gload16(gA + k0,         lA);
        gload16(gA + gstep + k0, lA + 2048);
        gload16(gB + k0,         lB);
        gload16(gB + gstep + k0, lB + 2048);
        asm volatile("s_waitcnt vmcnt(0)" ::: "memory");
        __syncthreads();

        short8 af[4], bfr[4];
        #pragma unroll
        for (int mi = 0; mi < 4; ++mi)
            af[mi] = *(const short8*)(As + (arow + mi * 16) * BK + koff);
        #pragma unroll
        for (int ni = 0; ni < 4; ++ni)
            bfr[ni] = *(const short8*)(Bs + (brow + ni * 16) * BK + koff);
        #pragma unroll
        for (int mi = 0; mi < 4; ++mi)
            #pragma unroll
            for (int ni = 0; ni < 4; ++ni)
                acc[mi][ni] = __builtin_amdgcn_mfma_f32_16x16x32_bf16(af[mi], bfr[ni], acc[mi][ni], 0, 0, 0);
        __syncthreads();
    }

    // LoRA tail: one extra K-step, A-operand = xa (scaled, padded), B-operand = Bp[adapter]
    {
        const int a = aidx[m0 >> 11];           // tile lies within one batch (2048 % 128 == 0)
        const u16* gxa = xa + (((size_t)(m0 + srow)) << 5) + skoff;
        const u16* gbp = Bp + (((((size_t)a) << 11) + n0 + srow) << 5) + skoff;
        gload16(gxa,             lA);
        gload16(gxa + (64 << 5), lA + 2048);
        gload16(gbp,             lB);
        gload16(gbp + (64 << 5), lB + 2048);
        asm volatile("s_waitcnt vmcnt(0)" ::: "memory");
        __syncthreads();

        short8 af[4], bfr[4];
        #pragma unroll
        for (int mi = 0; mi < 4; ++mi)
            af[mi] = *(const short8*)(As + (arow + mi * 16) * BK + koff);
        #pragma unroll
        for (int ni = 0; ni < 4; ++ni)
            bfr[ni] = *(const short8*)(Bs + (brow + ni * 16) * BK + koff);
        #pragma unroll
        for (int mi = 0; mi < 4; ++mi)
            #pragma unroll
            for (int ni = 0; ni < 4; ++ni)
                acc[mi][ni] = __builtin_amdgcn_mfma_f32_16x16x32_bf16(af[mi], bfr[ni], acc[mi][ni], 0, 0, 0);
    }

    // epilogue: D row = (lane>>4)*4 + r, col = lane&15
    #pragma unroll
    for (int mi = 0; mi < 4; ++mi) {
        #pragma unroll
        for (int ni = 0; ni < 4; ++ni) {
            const int nn = n0 + (wc << 6) + ni * 16 + (lane & 15);
            #pragma unroll
            for (int r = 0; r < 4; ++r) {
                const int mm = m0 + (wr << 6) + mi * 16 + ((lane >> 4) << 2) + r;
                out[(((size_t)mm) << 11) + nn] = acc[mi][ni][r];
            }
        }
    }
}

extern "C" void kernel_launch(void* const* d_in, const int* in_sizes, int n_in,
                              void* d_out, int out_size, void* d_ws, size_t ws_size,
                              hipStream_t stream) {
    const float* x  = (const float*)d_in[0];
    const float* W  = (const float*)d_in[1];
    const float* A  = (const float*)d_in[2];
    const float* Bm = (const float*)d_in[3];
    const float* sc = (const float*)d_in[4];
    const int* aidx = (const int*)d_in[5];
    float* out = (float*)d_out;

    // workspace layout (bytes): xb 128MiB | Wb 8MiB | At 512KiB | Bp 1MiB | xa 2MiB  (~139.5 MiB)
    char* ws = (char*)d_ws;
    u16* xb = (u16*)(ws);
    u16* Wb = (u16*)(ws + 134217728);
    u16* At = (u16*)(ws + 134217728 + 8388608);
    u16* Bp = (u16*)(ws + 134217728 + 8388608 + 524288);
    u16* xa = (u16*)(ws + 134217728 + 8388608 + 524288 + 1048576);

    hipLaunchKernelGGL(k_build_at,  dim3(1024),  dim3(256), 0, stream, A, At);
    hipLaunchKernelGGL(k_build_bp,  dim3(2048),  dim3(256), 0, stream, Bm, Bp);
    hipLaunchKernelGGL(k_cast_w,    dim3(2048),  dim3(256), 0, stream, W, Wb);
    hipLaunchKernelGGL(k_cast_x_xa, dim3(32768), dim3(256), 0, stream, x, At, sc, aidx, xb, xa);
    hipLaunchKernelGGL(k_gemm,      dim3(4096),  dim3(256), 0, stream, xb, Wb, xa, Bp, aidx, out);
}

// Round 2
// 468.803 us; speedup vs baseline: 1.4588x; 1.4588x over previous
//
#include <hip/hip_runtime.h>
#include <stdint.h>

typedef unsigned short u16;
typedef __attribute__((ext_vector_type(8))) short short8;
typedef __attribute__((ext_vector_type(4))) float f32x4;

// ---------- bf16 helpers (RNE) ----------
static __device__ __forceinline__ u16 f2bf(float f) {
    union { float f; uint32_t u; } c; c.f = f;
    uint32_t u = c.u;
    u += 0x7FFFu + ((u >> 16) & 1u);
    return (u16)(u >> 16);
}

// ---------- problem constants ----------
#define D_IN   2048
#define D_OUT  2048
#define MTOT   32768   // B*T = 16*2048
#define RP     64      // rank padded to one BK tile
#define BK     64

// async global->LDS, 16B per lane; LDS dest must be wavebase + lane*16 (linear)
__device__ __forceinline__ void gload16(const u16* g, u16* l) {
    __builtin_amdgcn_global_load_lds(
        (const __attribute__((address_space(1))) void*)g,
        (__attribute__((address_space(3))) void*)l, 16, 0, 0);
}

// ---------- prep: W fp32 -> bf16 ----------
__global__ __launch_bounds__(256) void k_cast_w(const float* __restrict__ W, u16* __restrict__ Wb) {
    int i = (blockIdx.x * 256 + threadIdx.x) * 8;
    const float4* p = (const float4*)(W + i);
    float4 v0 = p[0], v1 = p[1];
    short8 o;
    o[0]=f2bf(v0.x); o[1]=f2bf(v0.y); o[2]=f2bf(v0.z); o[3]=f2bf(v0.w);
    o[4]=f2bf(v1.x); o[5]=f2bf(v1.y); o[6]=f2bf(v1.z); o[7]=f2bf(v1.w);
    *(short8*)(Wb + i) = o;
}

// ---------- prep: x fp32 -> bf16, grid-stride ----------
__global__ __launch_bounds__(256) void k_cast_x(const float* __restrict__ x, u16* __restrict__ xb) {
    const size_t total = (size_t)MTOT * D_IN;
    const size_t stride = (size_t)gridDim.x * 256 * 8;
    for (size_t i = ((size_t)blockIdx.x * 256 + threadIdx.x) * 8; i < total; i += stride) {
        const float4* p = (const float4*)(x + i);
        float4 v0 = p[0], v1 = p[1];
        short8 o;
        o[0]=f2bf(v0.x); o[1]=f2bf(v0.y); o[2]=f2bf(v0.z); o[3]=f2bf(v0.w);
        o[4]=f2bf(v1.x); o[5]=f2bf(v1.y); o[6]=f2bf(v1.z); o[7]=f2bf(v1.w);
        *(short8*)(xb + i) = o;
    }
}

// ---------- prep: A (a,16,d) fp32 -> Apad (a,RP=64,d) bf16, rows 16..63 zero ----------
__global__ __launch_bounds__(256) void k_build_ap(const float* __restrict__ A, u16* __restrict__ Ap) {
    int i = blockIdx.x * 256 + threadIdx.x;   // over 8*64*2048 = 1048576
    int d = i & 2047;
    int r = (i >> 11) & 63;
    int a = i >> 17;
    float v = (r < 16) ? A[(((a << 4) + r) << 11) + d] : 0.0f;
    Ap[i] = f2bf(v);
}

// ---------- prep: Bm (a,n,16) fp32 -> Bp (a,n,RP=64) bf16, cols 16..63 zero ----------
__global__ __launch_bounds__(256) void k_build_bp(const float* __restrict__ Bm, u16* __restrict__ Bp) {
    int i = blockIdx.x * 256 + threadIdx.x;   // over 8*2048*64 = 1048576
    int j = i & 63;
    int n = (i >> 6) & 2047;
    int a = i >> 17;
    float v = (j < 16) ? Bm[((((a << 11) + n)) << 4) + j] : 0.0f;
    Bp[i] = f2bf(v);
}

// ---------- xa = s * (xb @ Apad^T) : skinny MFMA GEMM, M=32768 N=64 K=2048 ----------
__global__ __launch_bounds__(256) void k_xa(
    const u16* __restrict__ xb, const u16* __restrict__ Ap,
    const float* __restrict__ scal, const int* __restrict__ aidx,
    u16* __restrict__ xa)
{
    __shared__ __align__(16) u16 Xs[128 * BK];  // 16 KB
    __shared__ __align__(16) u16 Ps[64 * BK];   // 8 KB
    const int tid = threadIdx.x, lane = tid & 63, wid = tid >> 6;
    const int m0 = blockIdx.x << 7;
    const int a = aidx[m0 >> 11];
    const float s = scal[a];
    const int scol = ((lane & 7) ^ (lane >> 3)) << 3;   // swizzled source col (elems)
    const int wr = wid >> 1, wc = wid & 1;
    const int arow = (wr << 6) + (lane & 15);
    const int brow = (wc << 5) + (lane & 15);

    f32x4 acc[4][2];
    #pragma unroll
    for (int i = 0; i < 4; ++i) { acc[i][0] = 0.f; acc[i][1] = 0.f; }

    const u16* apg = Ap + ((size_t)a << 17);

    const u16* gX[4]; u16* lX[4];
    #pragma unroll
    for (int it = 0; it < 4; ++it) {
        const int chunk = (wid << 2) + it;
        const int row = (chunk << 3) + (lane >> 3);
        gX[it] = xb + ((size_t)(m0 + row) << 11) + scol;
        lX[it] = Xs + (chunk << 9) + (lane << 3);
    }
    const u16* gP[2]; u16* lP[2];
    #pragma unroll
    for (int it = 0; it < 2; ++it) {
        const int chunk = (wid << 1) + it;
        const int row = (chunk << 3) + (lane >> 3);
        gP[it] = apg + ((size_t)row << 11) + scol;
        lP[it] = Ps + (chunk << 9) + (lane << 3);
    }

    for (int kt = 0; kt < 32; ++kt) {
        const int k0 = kt << 6;
        #pragma unroll
        for (int it = 0; it < 4; ++it) gload16(gX[it] + k0, lX[it]);
        #pragma unroll
        for (int it = 0; it < 2; ++it) gload16(gP[it] + k0, lP[it]);
        asm volatile("s_waitcnt vmcnt(0)" ::: "memory");
        __syncthreads();
        #pragma unroll
        for (int kk = 0; kk < 2; ++kk) {
            const int ss = ((((kk << 2) + (lane >> 4)) ^ (lane & 7)) << 3);
            short8 af[4], bv[2];
            #pragma unroll
            for (int mi = 0; mi < 4; ++mi)
                af[mi] = *(const short8*)(Xs + (arow + mi * 16) * BK + ss);
            #pragma unroll
            for (int ni = 0; ni < 2; ++ni)
                bv[ni] = *(const short8*)(Ps + (brow + ni * 16) * BK + ss);
            #pragma unroll
            for (int mi = 0; mi < 4; ++mi)
                #pragma unroll
                for (int ni = 0; ni < 2; ++ni)
                    acc[mi][ni] = __builtin_amdgcn_mfma_f32_16x16x32_bf16(af[mi], bv[ni], acc[mi][ni], 0, 0, 0);
        }
        __syncthreads();
    }

    #pragma unroll
    for (int mi = 0; mi < 4; ++mi) {
        #pragma unroll
        for (int ni = 0; ni < 2; ++ni) {
            const int cc = (wc << 5) + ni * 16 + (lane & 15);
            #pragma unroll
            for (int rr = 0; rr < 4; ++rr) {
                const int mm = m0 + (wr << 6) + mi * 16 + ((lane >> 4) << 2) + rr;
                xa[((size_t)mm << 6) + cc] = f2bf(acc[mi][ni][rr] * s);
            }
        }
    }
}

// ---------- main GEMM + fused LoRA tail (128x128 tile, BK=64, XOR-swizzled LDS) ----------
__global__ __launch_bounds__(256) void k_gemm(
    const u16* __restrict__ xb, const u16* __restrict__ Wb,
    const u16* __restrict__ xa, const u16* __restrict__ Bp,
    const int* __restrict__ aidx, float* __restrict__ out)
{
    __shared__ __align__(16) u16 As[128 * BK];  // 16 KB
    __shared__ __align__(16) u16 Bs[128 * BK];  // 16 KB
    const int tid = threadIdx.x, lane = tid & 63, wid = tid >> 6;

    // XCD-aware bijective swizzle (nwg = 4096, %8 == 0)
    const int nb = gridDim.x;
    const int newbid = (blockIdx.x & 7) * (nb >> 3) + (blockIdx.x >> 3);
    const int bm = newbid >> 4;                 // 256 m-tiles
    const int bn = newbid & 15;                 // 16  n-tiles
    const int m0 = bm << 7, n0 = bn << 7;
    const int wr = wid >> 1, wc = wid & 1;      // 2x2 wave grid, 64x64 per wave

    f32x4 acc[4][4];
    #pragma unroll
    for (int i = 0; i < 4; ++i)
        #pragma unroll
        for (int j = 0; j < 4; ++j) acc[i][j] = 0.0f;

    const int scol = ((lane & 7) ^ (lane >> 3)) << 3;
    const int arow = (wr << 6) + (lane & 15);
    const int brow = (wc << 6) + (lane & 15);

    const u16* gA[4]; const u16* gB[4]; u16* lA[4]; u16* lB[4];
    int rowv[4];
    #pragma unroll
    for (int it = 0; it < 4; ++it) {
        const int chunk = (wid << 2) + it;
        const int row = (chunk << 3) + (lane >> 3);
        rowv[it] = row;
        gA[it] = xb + ((size_t)(m0 + row) << 11) + scol;
        gB[it] = Wb + ((size_t)(n0 + row) << 11) + scol;
        lA[it] = As + (chunk << 9) + (lane << 3);
        lB[it] = Bs + (chunk << 9) + (lane << 3);
    }

    #define COMPUTE_TILE()                                                                   \
        _Pragma("unroll")                                                                    \
        for (int kk = 0; kk < 2; ++kk) {                                                     \
            const int ss = ((((kk << 2) + (lane >> 4)) ^ (lane & 7)) << 3);                  \
            short8 af[4], bv[4];                                                             \
            _Pragma("unroll")                                                                \
            for (int mi = 0; mi < 4; ++mi)                                                   \
                af[mi] = *(const short8*)(As + (arow + mi * 16) * BK + ss);                   \
            _Pragma("unroll")                                                                \
            for (int ni = 0; ni < 4; ++ni)                                                   \
                bv[ni] = *(const short8*)(Bs + (brow + ni * 16) * BK + ss);                   \
            _Pragma("unroll")                                                                \
            for (int mi = 0; mi < 4; ++mi)                                                   \
                _Pragma("unroll")                                                            \
                for (int ni = 0; ni < 4; ++ni)                                               \
                    acc[mi][ni] = __builtin_amdgcn_mfma_f32_16x16x32_bf16(af[mi], bv[ni],    \
                                                                acc[mi][ni], 0, 0, 0);       \
        }

    for (int kt = 0; kt < 32; ++kt) {
        const int k0 = kt << 6;
        #pragma unroll
        for (int it = 0; it < 4; ++it) {
            gload16(gA[it] + k0, lA[it]);
            gload16(gB[it] + k0, lB[it]);
        }
        asm volatile("s_waitcnt vmcnt(0)" ::: "memory");
        __syncthreads();
        COMPUTE_TILE();
        __syncthreads();
    }

    // LoRA tail: one extra BK=64 step; A-op = xa (32768 x 64), B-op = Bp[adapter] (2048 x 64)
    {
        const int a = aidx[m0 >> 11];
        #pragma unroll
        for (int it = 0; it < 4; ++it) {
            gload16(xa + ((size_t)(m0 + rowv[it]) << 6) + scol, lA[it]);
            gload16(Bp + (((size_t)a << 11) + n0 + rowv[it]) * RP + scol, lB[it]);
        }
        asm volatile("s_waitcnt vmcnt(0)" ::: "memory");
        __syncthreads();
        COMPUTE_TILE();
    }
    #undef COMPUTE_TILE

    // epilogue: C row=(lane>>4)*4+r, col=lane&15
    #pragma unroll
    for (int mi = 0; mi < 4; ++mi) {
        #pragma unroll
        for (int ni = 0; ni < 4; ++ni) {
            const int nn = n0 + (wc << 6) + ni * 16 + (lane & 15);
            #pragma unroll
            for (int r = 0; r < 4; ++r) {
                const int mm = m0 + (wr << 6) + mi * 16 + ((lane >> 4) << 2) + r;
                out[((size_t)mm << 11) + nn] = acc[mi][ni][r];
            }
        }
    }
}

extern "C" void kernel_launch(void* const* d_in, const int* in_sizes, int n_in,
                              void* d_out, int out_size, void* d_ws, size_t ws_size,
                              hipStream_t stream) {
    const float* x  = (const float*)d_in[0];
    const float* W  = (const float*)d_in[1];
    const float* A  = (const float*)d_in[2];
    const float* Bm = (const float*)d_in[3];
    const float* sc = (const float*)d_in[4];
    const int* aidx = (const int*)d_in[5];
    float* out = (float*)d_out;

    // ws layout (bytes): xb 128MiB | Wb 8MiB | Apad 2MiB | Bp 2MiB | xa 4MiB = 144 MiB
    char* ws = (char*)d_ws;
    u16* xb = (u16*)(ws);
    u16* Wb = (u16*)(ws + 134217728);
    u16* Ap = (u16*)(ws + 134217728 + 8388608);
    u16* Bp = (u16*)(ws + 134217728 + 8388608 + 2097152);
    u16* xa = (u16*)(ws + 134217728 + 8388608 + 2097152 + 2097152);

    hipLaunchKernelGGL(k_build_ap, dim3(4096), dim3(256), 0, stream, A, Ap);
    hipLaunchKernelGGL(k_build_bp, dim3(4096), dim3(256), 0, stream, Bm, Bp);
    hipLaunchKernelGGL(k_cast_w,   dim3(2048), dim3(256), 0, stream, W, Wb);
    hipLaunchKernelGGL(k_cast_x,   dim3(2048), dim3(256), 0, stream, x, xb);
    hipLaunchKernelGGL(k_xa,       dim3(256),  dim3(256), 0, stream, xb, Ap, sc, aidx, xa);
    hipLaunchKernelGGL(k_gemm,     dim3(4096), dim3(256), 0, stream, xb, Wb, xa, Bp, aidx, out);
}